// Round 1
// baseline (453.187 us; speedup 1.0000x reference)
//
#include <hip/hip_runtime.h>
#include <cstdint>
#include <cstddef>

// ---------- types ----------
typedef __attribute__((ext_vector_type(8))) short short8;
typedef __attribute__((ext_vector_type(4))) short short4v;
typedef __attribute__((ext_vector_type(4))) float f32x4;

#define Bdim 2
#define Tdim 2048
#define Cdim 1024
#define Hdim 16
#define HDdim 64
#define Mdim (Bdim*Tdim)   // 4096
#define FFdim (4*Cdim)     // 4096

__device__ __forceinline__ uint16_t f2bf(float f) {
    union { float f; uint32_t u; } v; v.f = f;
    uint32_t x = v.u;
    uint32_t r = x + 0x7FFFu + ((x >> 16) & 1u);
    return (uint16_t)(r >> 16);
}
__device__ __forceinline__ float bf2f(uint16_t h) {
    union { float f; uint32_t u; } v; v.u = ((uint32_t)h) << 16; return v.f;
}

// ---------- elementwise cast f32 -> bf16 (vectorized x4) ----------
__global__ __launch_bounds__(256) void cast4_k(const float* __restrict__ in,
                                               uint16_t* __restrict__ out) {
    int i = (blockIdx.x * 256 + threadIdx.x) * 4;
    f32x4 v = *(const f32x4*)(in + i);
    short4v o;
#pragma unroll
    for (int j = 0; j < 4; ++j) o[j] = (short)f2bf(v[j]);
    *(short4v*)(out + i) = o;
}

// ---------- tiled transpose f32(R x Cc) -> bf16(Cc x R), batched ----------
__global__ __launch_bounds__(256) void transpose_tile(const float* __restrict__ in,
                                                      uint16_t* __restrict__ out,
                                                      int R, int Cc,
                                                      size_t ibs, size_t obs) {
    __shared__ uint16_t tile[32][33];
    const float* ip = in + (size_t)blockIdx.z * ibs;
    uint16_t* op = out + (size_t)blockIdx.z * obs;
    int r0 = blockIdx.x * 32, n0 = blockIdx.y * 32;
    int tx = threadIdx.x, ty = threadIdx.y;
#pragma unroll
    for (int i = 0; i < 4; ++i) {
        int r = ty + 8 * i;
        tile[r][tx] = f2bf(ip[(size_t)(r0 + r) * Cc + n0 + tx]);
    }
    __syncthreads();
#pragma unroll
    for (int i = 0; i < 4; ++i) {
        int n = ty + 8 * i;
        op[(size_t)(n0 + n) * R + r0 + tx] = tile[tx][n];
    }
}

// ---------- bf16 MFMA GEMM: C = A(MxK) * Bt(NxK)^T, fp32 accum ----------
// A row-major bf16, Bt row-major bf16 (i.e. B transposed). 128x128 tile, 4 waves.
template<bool BIAS, bool RELU, bool RESID, bool OUTF>
__global__ __launch_bounds__(256) void gemm_k(const uint16_t* __restrict__ A,
                                              const uint16_t* __restrict__ Bt,
                                              int M, int N, int K,
                                              float* __restrict__ outF,
                                              uint16_t* __restrict__ outB,
                                              const float* __restrict__ bias,
                                              const float* __restrict__ resid) {
    __shared__ uint16_t As[128][40]; // +8 pad: conflict-free b128 frag reads
    __shared__ uint16_t Bs[128][40];
    const int tid = threadIdx.x;
    const int wave = tid >> 6, lane = tid & 63;
    const int lg = lane >> 4, lr = lane & 15;
    const int wm = (wave >> 1) << 6, wn = (wave & 1) << 6;
    const size_t abase = (size_t)blockIdx.x * 128 * K;
    const size_t bbase = (size_t)blockIdx.y * 128 * K;

    f32x4 acc[4][4];
#pragma unroll
    for (int i = 0; i < 4; ++i)
#pragma unroll
        for (int j = 0; j < 4; ++j) acc[i][j] = (f32x4){0.f, 0.f, 0.f, 0.f};

    for (int k0 = 0; k0 < K; k0 += 32) {
#pragma unroll
        for (int it = 0; it < 2; ++it) {
            int c = it * 256 + tid;
            int row = c >> 2, col = (c & 3) << 3;
            short8 va = *(const short8*)(A + abase + (size_t)row * K + k0 + col);
            short8 vb = *(const short8*)(Bt + bbase + (size_t)row * K + k0 + col);
            *(short8*)&As[row][col] = va;
            *(short8*)&Bs[row][col] = vb;
        }
        __syncthreads();
        short8 af[4], bf[4];
#pragma unroll
        for (int m = 0; m < 4; ++m) af[m] = *(const short8*)&As[wm + 16 * m + lr][8 * lg];
#pragma unroll
        for (int n = 0; n < 4; ++n) bf[n] = *(const short8*)&Bs[wn + 16 * n + lr][8 * lg];
#pragma unroll
        for (int m = 0; m < 4; ++m)
#pragma unroll
            for (int n = 0; n < 4; ++n)
                acc[m][n] = __builtin_amdgcn_mfma_f32_16x16x32_bf16(af[m], bf[n], acc[m][n], 0, 0, 0);
        __syncthreads();
    }
    // epilogue: C/D layout col=lane&15, row=4*(lane>>4)+reg  [verified m89/m91]
#pragma unroll
    for (int n = 0; n < 4; ++n) {
        const int col = (blockIdx.y << 7) + wn + 16 * n + lr;
        const float bv = BIAS ? bias[col] : 0.f;
#pragma unroll
        for (int m = 0; m < 4; ++m) {
#pragma unroll
            for (int r = 0; r < 4; ++r) {
                const int row = (blockIdx.x << 7) + wm + 16 * m + 4 * lg + r;
                float v = acc[m][n][r] + bv;
                if (RELU) v = fmaxf(v, 0.f);
                if (RESID) v += resid[(size_t)row * N + col];
                if (OUTF) outF[(size_t)row * N + col] = v;
                else      outB[(size_t)row * N + col] = f2bf(v);
            }
        }
    }
}

// ---------- flash attention: 1 wave per 16-row q-tile, kv chunks of 32 ----------
// qkv: (B*T) x 3072 bf16 rows = [q | k | v], per-head slices of 64.
__global__ __launch_bounds__(64) void attn_k(const uint16_t* __restrict__ qkv,
                                             uint16_t* __restrict__ o) {
    const int lane = threadIdx.x;
    const int lg = lane >> 4, lr = lane & 15;
    const int qb = blockIdx.x << 4;
    const int bh = blockIdx.y;
    const int b = bh >> 4, h = bh & 15;
    const size_t rs = 3 * Cdim;
    const uint16_t* qp = qkv + (size_t)b * Tdim * rs + (size_t)h * HDdim;
    const uint16_t* kp = qp + Cdim;
    const uint16_t* vp = qp + 2 * Cdim;

    // Q fragments, pre-scaled by 1/sqrt(64)=0.125 (exact in bf16)
    short8 qf[2];
#pragma unroll
    for (int c = 0; c < 2; ++c) {
        short8 raw = *(const short8*)(qp + (size_t)(qb + lr) * rs + 32 * c + 8 * lg);
#pragma unroll
        for (int j = 0; j < 8; ++j)
            qf[c][j] = (short)f2bf(bf2f((uint16_t)raw[j]) * 0.125f);
    }

    float m_run = -__builtin_inff(), l_run = 0.f;
    f32x4 oacc[4];
#pragma unroll
    for (int t = 0; t < 4; ++t) oacc[t] = (f32x4){0.f, 0.f, 0.f, 0.f};

    const int nch = (qb + 47) >> 5; // chunks of 32 kv covering [0, qb+16)
    for (int ch = 0; ch < nch; ++ch) {
        const int kvb = ch << 5;
        // S^T = K * Q^T : lane holds S^T[kv=16u+4lg+r][q=lr]
        f32x4 s[2];
#pragma unroll
        for (int u = 0; u < 2; ++u) {
            const uint16_t* krow = kp + (size_t)(kvb + 16 * u + lr) * rs;
            short8 k0 = *(const short8*)(krow + 8 * lg);
            short8 k1 = *(const short8*)(krow + 32 + 8 * lg);
            f32x4 z = (f32x4){0.f, 0.f, 0.f, 0.f};
            z = __builtin_amdgcn_mfma_f32_16x16x32_bf16(k0, qf[0], z, 0, 0, 0);
            z = __builtin_amdgcn_mfma_f32_16x16x32_bf16(k1, qf[1], z, 0, 0, 0);
            s[u] = z;
        }
        const int qg = qb + lr;
        float p[2][4];
        float mx = -__builtin_inff();
#pragma unroll
        for (int u = 0; u < 2; ++u)
#pragma unroll
            for (int r = 0; r < 4; ++r) {
                int kv = kvb + 16 * u + 4 * lg + r;
                float sv = (kv <= qg) ? s[u][r] : -__builtin_inff();
                p[u][r] = sv;
                mx = fmaxf(mx, sv);
            }
        mx = fmaxf(mx, __shfl_xor(mx, 16));
        mx = fmaxf(mx, __shfl_xor(mx, 32));
        const float m_new = fmaxf(m_run, mx);
        const float alpha = __expf(m_run - m_new); // first chunk: exp(-inf)=0
        float ps = 0.f;
#pragma unroll
        for (int u = 0; u < 2; ++u)
#pragma unroll
            for (int r = 0; r < 4; ++r) {
                float e = __expf(p[u][r] - m_new);
                p[u][r] = e; ps += e;
            }
        ps += __shfl_xor(ps, 16);
        ps += __shfl_xor(ps, 32);
        l_run = l_run * alpha + ps;
        m_run = m_new;
        // P as B-operand with custom slot map kappa'(g,j): j<4 -> 4g+j (tile u=0),
        // j>=4 -> 16+4g+(j-4) (tile u=1) -- matches S output regs, zero shuffles.
        short8 pb;
#pragma unroll
        for (int j = 0; j < 4; ++j) { pb[j] = (short)f2bf(p[0][j]); pb[j + 4] = (short)f2bf(p[1][j]); }
        // O^T += V^T * P^T, same kappa' on V's s-index
#pragma unroll
        for (int t = 0; t < 4; ++t) {
            short8 vf;
#pragma unroll
            for (int j = 0; j < 4; ++j) {
                vf[j]     = (short)vp[(size_t)(kvb + 4 * lg + j) * rs + 16 * t + lr];
                vf[j + 4] = (short)vp[(size_t)(kvb + 16 + 4 * lg + j) * rs + 16 * t + lr];
            }
            f32x4 oa = oacc[t];
#pragma unroll
            for (int r = 0; r < 4; ++r) oa[r] *= alpha;
            oacc[t] = __builtin_amdgcn_mfma_f32_16x16x32_bf16(vf, pb, oa, 0, 0, 0);
        }
    }
    const float inv = 1.f / l_run;
    uint16_t* orow = o + (size_t)(b * Tdim + qb + lr) * Cdim + h * HDdim;
#pragma unroll
    for (int t = 0; t < 4; ++t)
#pragma unroll
        for (int r = 0; r < 4; ++r)
            orow[16 * t + 4 * lg + r] = f2bf(oacc[t][r] * inv);
}

// ---------- LayerNorm over rows of 1024, fp32 in, fp32 and/or bf16 out ----------
__global__ __launch_bounds__(256) void ln_k(const float* __restrict__ in,
                                            const float* __restrict__ g,
                                            const float* __restrict__ be,
                                            float* __restrict__ outF,
                                            uint16_t* __restrict__ outB) {
    const int row = blockIdx.x, tid = threadIdx.x;
    const float* x = in + (size_t)row * Cdim;
    f32x4 xv = *(const f32x4*)(x + tid * 4);
    float s = xv[0] + xv[1] + xv[2] + xv[3];
    float q = xv[0] * xv[0] + xv[1] * xv[1] + xv[2] * xv[2] + xv[3] * xv[3];
#pragma unroll
    for (int off = 1; off < 64; off <<= 1) { s += __shfl_xor(s, off); q += __shfl_xor(q, off); }
    __shared__ float sm[4], sq[4];
    if ((tid & 63) == 0) { sm[tid >> 6] = s; sq[tid >> 6] = q; }
    __syncthreads();
    s = sm[0] + sm[1] + sm[2] + sm[3];
    q = sq[0] + sq[1] + sq[2] + sq[3];
    const float mu = s * (1.f / 1024.f);
    const float var = q * (1.f / 1024.f) - mu * mu;
    const float rstd = rsqrtf(var + 1e-5f);
#pragma unroll
    for (int j = 0; j < 4; ++j) {
        int col = tid * 4 + j;
        float y = (xv[j] - mu) * rstd * g[col] + be[col];
        if (outF) outF[(size_t)row * Cdim + col] = y;
        if (outB) outB[(size_t)row * Cdim + col] = f2bf(y);
    }
}

// ---------- launch ----------
extern "C" void kernel_launch(void* const* d_in, const int* in_sizes, int n_in,
                              void* d_out, int out_size, void* d_ws, size_t ws_size,
                              hipStream_t stream) {
    const float* x   = (const float*)d_in[0];
    const float* Wq  = (const float*)d_in[1];
    const float* Wk  = (const float*)d_in[2];
    const float* Wv  = (const float*)d_in[3];
    const float* Wp  = (const float*)d_in[4];
    const float* bp  = (const float*)d_in[5];
    const float* W1  = (const float*)d_in[6];
    const float* b1  = (const float*)d_in[7];
    const float* W2  = (const float*)d_in[8];
    const float* b2  = (const float*)d_in[9];
    const float* g1  = (const float*)d_in[10];
    const float* be1 = (const float*)d_in[11];
    const float* g2  = (const float*)d_in[12];
    const float* be2 = (const float*)d_in[13];
    float* out = (float*)d_out;

    char* ws = (char*)d_ws;
    uint16_t* xb    = (uint16_t*)(ws + 0);          //  8 MB : x bf16
    uint16_t* wqkv  = (uint16_t*)(ws + 8388608);    //  6 MB : (3072 x 1024) packed W_qkv^T
    uint16_t* qkv   = (uint16_t*)(ws + 14680064);   // 24 MB : (4096 x 3072)
    uint16_t* obuf  = (uint16_t*)(ws + 39845888);   //  8 MB : attn out (4096 x 1024)
    uint16_t* h1    = (uint16_t*)(ws + 14680064);   // 32 MB : FFN hidden, aliases qkv+obuf (both dead)
    uint16_t* wpt   = (uint16_t*)(ws + 48234496);   //  2 MB : Wp^T
    float*    resid = (float*)   (ws + 50331648);   // 16 MB : residual (reused for both)
    uint16_t* x1b   = (uint16_t*)(ws + 67108864);   //  8 MB : ln1 out bf16
    float*    x1f   = (float*)   (ws + 75497472);   // 16 MB : ln1 out fp32
    uint16_t* w1t   = (uint16_t*)(ws + 92274688);   //  8 MB : W1^T
    uint16_t* w2t   = (uint16_t*)(ws + 100663296);  //  8 MB : W2^T   (total ~104 MB)

    // pack / cast
    cast4_k<<<4096, 256, 0, stream>>>(x, xb);
    transpose_tile<<<dim3(32, 2, 16), dim3(32, 8), 0, stream>>>(Wq, wqkv,           1024, 64, 65536, 65536);
    transpose_tile<<<dim3(32, 2, 16), dim3(32, 8), 0, stream>>>(Wk, wqkv + 1048576, 1024, 64, 65536, 65536);
    transpose_tile<<<dim3(32, 2, 16), dim3(32, 8), 0, stream>>>(Wv, wqkv + 2097152, 1024, 64, 65536, 65536);
    transpose_tile<<<dim3(32, 32, 1),  dim3(32, 8), 0, stream>>>(Wp, wpt, 1024, 1024, 0, 0);
    transpose_tile<<<dim3(32, 128, 1), dim3(32, 8), 0, stream>>>(W1, w1t, 1024, 4096, 0, 0);
    transpose_tile<<<dim3(128, 32, 1), dim3(32, 8), 0, stream>>>(W2, w2t, 4096, 1024, 0, 0);

    // QKV projection
    gemm_k<false, false, false, false><<<dim3(32, 24), 256, 0, stream>>>(
        xb, wqkv, Mdim, 3 * Cdim, Cdim, nullptr, qkv, nullptr, nullptr);
    // attention
    attn_k<<<dim3(Tdim / 16, Bdim * Hdim), 64, 0, stream>>>(qkv, obuf);
    // output projection + bias + residual(x) -> resid (fp32)
    gemm_k<true, false, true, true><<<dim3(32, 8), 256, 0, stream>>>(
        obuf, wpt, Mdim, Cdim, Cdim, resid, nullptr, bp, x);
    // LN1 -> x1 (fp32 + bf16)
    ln_k<<<Mdim, 256, 0, stream>>>(resid, g1, be1, x1f, x1b);
    // FFN1: relu(x1 @ W1 + b1) -> h1 bf16
    gemm_k<true, true, false, false><<<dim3(32, 32), 256, 0, stream>>>(
        x1b, w1t, Mdim, FFdim, Cdim, nullptr, h1, b1, nullptr);
    // FFN2: h1 @ W2 + b2 + x1 -> resid (fp32)
    gemm_k<true, false, true, true><<<dim3(32, 8), 256, 0, stream>>>(
        h1, w2t, Mdim, Cdim, FFdim, resid, nullptr, b2, x1f);
    // LN2 -> final output fp32
    ln_k<<<Mdim, 256, 0, stream>>>(resid, g2, be2, out, nullptr);
}

// Round 2
// 439.948 us; speedup vs baseline: 1.0301x; 1.0301x over previous
//
#include <hip/hip_runtime.h>
#include <cstdint>
#include <cstddef>

// ---------- types ----------
typedef __attribute__((ext_vector_type(8))) short short8;
typedef __attribute__((ext_vector_type(4))) short short4v;
typedef __attribute__((ext_vector_type(4))) float f32x4;

#define Bdim 2
#define Tdim 2048
#define Cdim 1024
#define Hdim 16
#define HDdim 64
#define Mdim (Bdim*Tdim)   // 4096
#define FFdim (4*Cdim)     // 4096

__device__ __forceinline__ uint16_t f2bf(float f) {
    union { float f; uint32_t u; } v; v.f = f;
    uint32_t x = v.u;
    uint32_t r = x + 0x7FFFu + ((x >> 16) & 1u);
    return (uint16_t)(r >> 16);
}
__device__ __forceinline__ float bf2f(uint16_t h) {
    union { float f; uint32_t u; } v; v.u = ((uint32_t)h) << 16; return v.f;
}

// async global->LDS, 16B per lane. dst must be wave-uniform base; HW adds lane*16.
__device__ __forceinline__ void gload_lds16(const uint16_t* g, uint16_t* l) {
    __builtin_amdgcn_global_load_lds(
        (const __attribute__((address_space(1))) void*)g,
        (__attribute__((address_space(3))) void*)l, 16, 0, 0);
}

// ---------- elementwise cast f32 -> bf16 (vectorized x4) ----------
__global__ __launch_bounds__(256) void cast4_k(const float* __restrict__ in,
                                               uint16_t* __restrict__ out) {
    int i = (blockIdx.x * 256 + threadIdx.x) * 4;
    f32x4 v = *(const f32x4*)(in + i);
    short4v o;
#pragma unroll
    for (int j = 0; j < 4; ++j) o[j] = (short)f2bf(v[j]);
    *(short4v*)(out + i) = o;
}

// ---------- tiled transpose f32(R x Cc) -> bf16(Cc x R), batched ----------
__global__ __launch_bounds__(256) void transpose_tile(const float* __restrict__ in,
                                                      uint16_t* __restrict__ out,
                                                      int R, int Cc,
                                                      size_t ibs, size_t obs) {
    __shared__ uint16_t tile[32][33];
    const float* ip = in + (size_t)blockIdx.z * ibs;
    uint16_t* op = out + (size_t)blockIdx.z * obs;
    int r0 = blockIdx.x * 32, n0 = blockIdx.y * 32;
    int tx = threadIdx.x, ty = threadIdx.y;
#pragma unroll
    for (int i = 0; i < 4; ++i) {
        int r = ty + 8 * i;
        tile[r][tx] = f2bf(ip[(size_t)(r0 + r) * Cc + n0 + tx]);
    }
    __syncthreads();
#pragma unroll
    for (int i = 0; i < 4; ++i) {
        int n = ty + 8 * i;
        op[(size_t)(n0 + n) * R + r0 + tx] = tile[tx][n];
    }
}

// ---------- per-head V transpose: qkv V slice -> vT[bh][d=64][t=T] bf16 ----------
__global__ __launch_bounds__(256) void vtrans_k(const uint16_t* __restrict__ qkv,
                                                uint16_t* __restrict__ vT) {
    __shared__ uint16_t tile[32][33];
    const int bh = blockIdx.z, b = bh >> 4, h = bh & 15;
    const uint16_t* vp = qkv + (size_t)b * Tdim * (3 * Cdim) + 2 * Cdim + h * HDdim;
    uint16_t* op = vT + (size_t)bh * HDdim * Tdim;
    const int t0 = blockIdx.x * 32, d0 = blockIdx.y * 32;
    const int tx = threadIdx.x, ty = threadIdx.y;
#pragma unroll
    for (int i = 0; i < 4; ++i) {
        int r = ty + 8 * i;
        tile[r][tx] = vp[(size_t)(t0 + r) * (3 * Cdim) + d0 + tx];
    }
    __syncthreads();
#pragma unroll
    for (int i = 0; i < 4; ++i) {
        int d = ty + 8 * i;
        op[(size_t)(d0 + d) * Tdim + t0 + tx] = tile[tx][d];
    }
}

// ---------- bf16 MFMA GEMM: C = A(MxK) * Bt(NxK)^T, fp32 accum ----------
// m97 structure: linear [128][32] LDS, global_load_lds width-16 staging, 2-barrier.
template<bool BIAS, bool RELU, bool RESID, bool OUTF>
__global__ __launch_bounds__(256) void gemm_k(const uint16_t* __restrict__ A,
                                              const uint16_t* __restrict__ Bt,
                                              int M, int N, int K,
                                              float* __restrict__ outF,
                                              uint16_t* __restrict__ outB,
                                              const float* __restrict__ bias,
                                              const float* __restrict__ resid) {
    __shared__ uint16_t As[128 * 32];
    __shared__ uint16_t Bs[128 * 32];
    const int tid = threadIdx.x;
    const int wave = tid >> 6, lane = tid & 63;
    const int lg = lane >> 4, lr = lane & 15;
    const int wm = (wave >> 1) << 6, wn = (wave & 1) << 6;
    // staging: seg = it*256 + tid -> LDS bytes seg*16 ; global row seg>>2, col (seg&3)*8
    const uint16_t* ag = A + (size_t)blockIdx.x * 128 * K + (size_t)(tid >> 2) * K + (tid & 3) * 8;
    const uint16_t* bg = Bt + (size_t)blockIdx.y * 128 * K + (size_t)(tid >> 2) * K + (tid & 3) * 8;
    const size_t rstep = (size_t)64 * K; // it=1: +64 rows
    uint16_t* al = As + wave * 512;      // wave-uniform LDS base (elements)
    uint16_t* bl = Bs + wave * 512;

    f32x4 acc[4][4];
#pragma unroll
    for (int i = 0; i < 4; ++i)
#pragma unroll
        for (int j = 0; j < 4; ++j) acc[i][j] = (f32x4){0.f, 0.f, 0.f, 0.f};

    for (int k0 = 0; k0 < K; k0 += 32) {
        gload_lds16(ag + k0, al);
        gload_lds16(ag + k0 + rstep, al + 2048);
        gload_lds16(bg + k0, bl);
        gload_lds16(bg + k0 + rstep, bl + 2048);
        __syncthreads();   // drains vmcnt: staged data visible
        short8 af[4], bfr[4];
#pragma unroll
        for (int m = 0; m < 4; ++m) af[m] = *(const short8*)(As + (wm + 16 * m + lr) * 32 + 8 * lg);
#pragma unroll
        for (int n = 0; n < 4; ++n) bfr[n] = *(const short8*)(Bs + (wn + 16 * n + lr) * 32 + 8 * lg);
#pragma unroll
        for (int m = 0; m < 4; ++m)
#pragma unroll
            for (int n = 0; n < 4; ++n)
                acc[m][n] = __builtin_amdgcn_mfma_f32_16x16x32_bf16(af[m], bfr[n], acc[m][n], 0, 0, 0);
        __syncthreads();   // all ds_reads done before next-stage overwrite
    }
    // epilogue: C/D layout col=lane&15, row=4*(lane>>4)+reg  [verified m89/m91]
#pragma unroll
    for (int n = 0; n < 4; ++n) {
        const int col = (blockIdx.y << 7) + wn + 16 * n + lr;
        const float bv = BIAS ? bias[col] : 0.f;
#pragma unroll
        for (int m = 0; m < 4; ++m) {
#pragma unroll
            for (int r = 0; r < 4; ++r) {
                const int row = (blockIdx.x << 7) + wm + 16 * m + 4 * lg + r;
                float v = acc[m][n][r] + bv;
                if (RELU) v = fmaxf(v, 0.f);
                if (RESID) v += resid[(size_t)row * N + col];
                if (OUTF) outF[(size_t)row * N + col] = v;
                else      outB[(size_t)row * N + col] = f2bf(v);
            }
        }
    }
}

// ---------- flash attention: 1 wave per 32 q-rows (2 groups of 16), kv chunks of 32 ----------
// qkv rows: [q | k | v] per token; vT: [bh][64][T] pre-transposed V.
__global__ __launch_bounds__(64) void attn_k(const uint16_t* __restrict__ qkv,
                                             const uint16_t* __restrict__ vT,
                                             uint16_t* __restrict__ o) {
    const int lane = threadIdx.x;
    const int lg = lane >> 4, lr = lane & 15;
    const int qb = blockIdx.x << 5;          // 32 q-rows per wave
    const int bh = blockIdx.y;
    const int b = bh >> 4, h = bh & 15;
    const size_t rs = 3 * Cdim;
    const uint16_t* qp = qkv + (size_t)b * Tdim * rs + (size_t)h * HDdim;
    const uint16_t* kp = qp + Cdim;
    const uint16_t* vtp = vT + (size_t)bh * HDdim * Tdim;

    // Q fragments for both groups, pre-scaled by 0.125 (exact in bf16)
    short8 qf[2][2];
#pragma unroll
    for (int g = 0; g < 2; ++g)
#pragma unroll
        for (int c = 0; c < 2; ++c) {
            short8 raw = *(const short8*)(qp + (size_t)(qb + 16 * g + lr) * rs + 32 * c + 8 * lg);
#pragma unroll
            for (int j = 0; j < 8; ++j)
                qf[g][c][j] = (short)f2bf(bf2f((uint16_t)raw[j]) * 0.125f);
        }

    // per-t V^T row bases (d = 16t+lr)
    const uint16_t* vrow[4];
#pragma unroll
    for (int t = 0; t < 4; ++t) vrow[t] = vtp + (size_t)(16 * t + lr) * Tdim + 4 * lg;

    float m_run[2] = {-__builtin_inff(), -__builtin_inff()};
    float l_run[2] = {0.f, 0.f};
    f32x4 oacc[2][4];
#pragma unroll
    for (int g = 0; g < 2; ++g)
#pragma unroll
        for (int t = 0; t < 4; ++t) oacc[g][t] = (f32x4){0.f, 0.f, 0.f, 0.f};

    const int nch = blockIdx.x + 1; // chunks of 32 kv covering [0, qb+32)
    for (int ch = 0; ch < nch; ++ch) {
        const int kvb = ch << 5;
        // shared K fragments (both q-groups)
        short8 kf[2][2];
#pragma unroll
        for (int u = 0; u < 2; ++u) {
            const uint16_t* krow = kp + (size_t)(kvb + 16 * u + lr) * rs + 8 * lg;
            kf[u][0] = *(const short8*)(krow);
            kf[u][1] = *(const short8*)(krow + 32);
        }
        // shared V^T fragments: kappa'(lg,j) = 4lg+j (j<4), 16+4lg+(j-4) (j>=4)
        short8 vf[4];
#pragma unroll
        for (int t = 0; t < 4; ++t) {
            short4v v0 = *(const short4v*)(vrow[t] + kvb);
            short4v v1 = *(const short4v*)(vrow[t] + kvb + 16);
            vf[t] = (short8){v0[0], v0[1], v0[2], v0[3], v1[0], v1[1], v1[2], v1[3]};
        }
#pragma unroll
        for (int g = 0; g < 2; ++g) {
            // S^T = K * Q^T : lane holds S^T[kv=16u+4lg+r][q=lr]
            f32x4 s[2];
#pragma unroll
            for (int u = 0; u < 2; ++u) {
                f32x4 z = (f32x4){0.f, 0.f, 0.f, 0.f};
                z = __builtin_amdgcn_mfma_f32_16x16x32_bf16(kf[u][0], qf[g][0], z, 0, 0, 0);
                z = __builtin_amdgcn_mfma_f32_16x16x32_bf16(kf[u][1], qf[g][1], z, 0, 0, 0);
                s[u] = z;
            }
            const int qg = qb + 16 * g + lr;
            float p[2][4];
            float mx = -__builtin_inff();
#pragma unroll
            for (int u = 0; u < 2; ++u)
#pragma unroll
                for (int r = 0; r < 4; ++r) {
                    int kv = kvb + 16 * u + 4 * lg + r;
                    float sv = (kv <= qg) ? s[u][r] : -__builtin_inff();
                    p[u][r] = sv;
                    mx = fmaxf(mx, sv);
                }
            mx = fmaxf(mx, __shfl_xor(mx, 16));
            mx = fmaxf(mx, __shfl_xor(mx, 32));
            const float m_new = fmaxf(m_run[g], mx);
            const float alpha = __expf(m_run[g] - m_new);
            float ps = 0.f;
#pragma unroll
            for (int u = 0; u < 2; ++u)
#pragma unroll
                for (int r = 0; r < 4; ++r) {
                    float e = __expf(p[u][r] - m_new);
                    p[u][r] = e; ps += e;
                }
            ps += __shfl_xor(ps, 16);
            ps += __shfl_xor(ps, 32);
            l_run[g] = l_run[g] * alpha + ps;
            m_run[g] = m_new;
            // P as B-operand with kappa' map -- matches S output regs, zero shuffles
            short8 pb;
#pragma unroll
            for (int j = 0; j < 4; ++j) { pb[j] = (short)f2bf(p[0][j]); pb[j + 4] = (short)f2bf(p[1][j]); }
            // O^T += V^T * P^T (same kappa' on V's kv index)
#pragma unroll
            for (int t = 0; t < 4; ++t) {
                f32x4 oa = oacc[g][t];
#pragma unroll
                for (int r = 0; r < 4; ++r) oa[r] *= alpha;
                oacc[g][t] = __builtin_amdgcn_mfma_f32_16x16x32_bf16(vf[t], pb, oa, 0, 0, 0);
            }
        }
    }
#pragma unroll
    for (int g = 0; g < 2; ++g) {
        const float inv = 1.f / l_run[g];
        uint16_t* orow = o + (size_t)(b * Tdim + qb + 16 * g + lr) * Cdim + h * HDdim;
#pragma unroll
        for (int t = 0; t < 4; ++t)
#pragma unroll
            for (int r = 0; r < 4; ++r)
                orow[16 * t + 4 * lg + r] = f2bf(oacc[g][t][r] * inv);
    }
}

// ---------- LayerNorm over rows of 1024, fp32 in, fp32 and/or bf16 out ----------
__global__ __launch_bounds__(256) void ln_k(const float* __restrict__ in,
                                            const float* __restrict__ g,
                                            const float* __restrict__ be,
                                            float* __restrict__ outF,
                                            uint16_t* __restrict__ outB) {
    const int row = blockIdx.x, tid = threadIdx.x;
    const float* x = in + (size_t)row * Cdim;
    f32x4 xv = *(const f32x4*)(x + tid * 4);
    float s = xv[0] + xv[1] + xv[2] + xv[3];
    float q = xv[0] * xv[0] + xv[1] * xv[1] + xv[2] * xv[2] + xv[3] * xv[3];
#pragma unroll
    for (int off = 1; off < 64; off <<= 1) { s += __shfl_xor(s, off); q += __shfl_xor(q, off); }
    __shared__ float sm[4], sq[4];
    if ((tid & 63) == 0) { sm[tid >> 6] = s; sq[tid >> 6] = q; }
    __syncthreads();
    s = sm[0] + sm[1] + sm[2] + sm[3];
    q = sq[0] + sq[1] + sq[2] + sq[3];
    const float mu = s * (1.f / 1024.f);
    const float var = q * (1.f / 1024.f) - mu * mu;
    const float rstd = rsqrtf(var + 1e-5f);
#pragma unroll
    for (int j = 0; j < 4; ++j) {
        int col = tid * 4 + j;
        float y = (xv[j] - mu) * rstd * g[col] + be[col];
        if (outF) outF[(size_t)row * Cdim + col] = y;
        if (outB) outB[(size_t)row * Cdim + col] = f2bf(y);
    }
}

// ---------- launch ----------
extern "C" void kernel_launch(void* const* d_in, const int* in_sizes, int n_in,
                              void* d_out, int out_size, void* d_ws, size_t ws_size,
                              hipStream_t stream) {
    const float* x   = (const float*)d_in[0];
    const float* Wq  = (const float*)d_in[1];
    const float* Wk  = (const float*)d_in[2];
    const float* Wv  = (const float*)d_in[3];
    const float* Wp  = (const float*)d_in[4];
    const float* bp  = (const float*)d_in[5];
    const float* W1  = (const float*)d_in[6];
    const float* b1  = (const float*)d_in[7];
    const float* W2  = (const float*)d_in[8];
    const float* b2  = (const float*)d_in[9];
    const float* g1  = (const float*)d_in[10];
    const float* be1 = (const float*)d_in[11];
    const float* g2  = (const float*)d_in[12];
    const float* be2 = (const float*)d_in[13];
    float* out = (float*)d_out;

    char* ws = (char*)d_ws;
    uint16_t* xb    = (uint16_t*)(ws + 0);          //  8 MB : x bf16
    uint16_t* wqkv  = (uint16_t*)(ws + 8388608);    //  6 MB : (3072 x 1024) packed W_qkv^T
    uint16_t* qkv   = (uint16_t*)(ws + 14680064);   // 24 MB : (4096 x 3072)
    uint16_t* obuf  = (uint16_t*)(ws + 39845888);   //  8 MB : attn out (4096 x 1024)
    uint16_t* h1    = (uint16_t*)(ws + 14680064);   // 32 MB : FFN hidden, aliases qkv+obuf (both dead)
    uint16_t* wpt   = (uint16_t*)(ws + 48234496);   //  2 MB : Wp^T
    float*    resid = (float*)   (ws + 50331648);   // 16 MB : residual (reused for both)
    uint16_t* x1b   = (uint16_t*)(ws + 67108864);   //  8 MB : ln1 out bf16
    float*    x1f   = (float*)   (ws + 75497472);   // 16 MB : ln1 out fp32 (written after attn)
    uint16_t* vT    = (uint16_t*)(ws + 75497472);   //  8 MB : V^T, aliases x1f (dead by LN1)
    uint16_t* w1t   = (uint16_t*)(ws + 92274688);   //  8 MB : W1^T
    uint16_t* w2t   = (uint16_t*)(ws + 100663296);  //  8 MB : W2^T   (total ~104 MB)

    // pack / cast
    cast4_k<<<4096, 256, 0, stream>>>(x, xb);
    transpose_tile<<<dim3(32, 2, 16), dim3(32, 8), 0, stream>>>(Wq, wqkv,           1024, 64, 65536, 65536);
    transpose_tile<<<dim3(32, 2, 16), dim3(32, 8), 0, stream>>>(Wk, wqkv + 1048576, 1024, 64, 65536, 65536);
    transpose_tile<<<dim3(32, 2, 16), dim3(32, 8), 0, stream>>>(Wv, wqkv + 2097152, 1024, 64, 65536, 65536);
    transpose_tile<<<dim3(32, 32, 1),  dim3(32, 8), 0, stream>>>(Wp, wpt, 1024, 1024, 0, 0);
    transpose_tile<<<dim3(32, 128, 1), dim3(32, 8), 0, stream>>>(W1, w1t, 1024, 4096, 0, 0);
    transpose_tile<<<dim3(128, 32, 1), dim3(32, 8), 0, stream>>>(W2, w2t, 4096, 1024, 0, 0);

    // QKV projection
    gemm_k<false, false, false, false><<<dim3(32, 24), 256, 0, stream>>>(
        xb, wqkv, Mdim, 3 * Cdim, Cdim, nullptr, qkv, nullptr, nullptr);
    // V^T pack for attention
    vtrans_k<<<dim3(64, 2, 32), dim3(32, 8), 0, stream>>>(qkv, vT);
    // attention
    attn_k<<<dim3(Tdim / 32, Bdim * Hdim), 64, 0, stream>>>(qkv, vT, obuf);
    // output projection + bias + residual(x) -> resid (fp32)
    gemm_k<true, false, true, true><<<dim3(32, 8), 256, 0, stream>>>(
        obuf, wpt, Mdim, Cdim, Cdim, resid, nullptr, bp, x);
    // LN1 -> x1 (fp32 + bf16)
    ln_k<<<Mdim, 256, 0, stream>>>(resid, g1, be1, x1f, x1b);
    // FFN1: relu(x1 @ W1 + b1) -> h1 bf16
    gemm_k<true, true, false, false><<<dim3(32, 32), 256, 0, stream>>>(
        x1b, w1t, Mdim, FFdim, Cdim, nullptr, h1, b1, nullptr);
    // FFN2: h1 @ W2 + b2 + x1 -> resid (fp32)
    gemm_k<true, false, true, true><<<dim3(32, 8), 256, 0, stream>>>(
        h1, w2t, Mdim, Cdim, FFdim, resid, nullptr, b2, x1f);
    // LN2 -> final output fp32
    ln_k<<<Mdim, 256, 0, stream>>>(resid, g2, be2, out, nullptr);
}

// Round 3
// 332.341 us; speedup vs baseline: 1.3636x; 1.3238x over previous
//
#include <hip/hip_runtime.h>
#include <cstdint>
#include <cstddef>

// ---------- types ----------
typedef __attribute__((ext_vector_type(8))) short short8;
typedef __attribute__((ext_vector_type(4))) short short4v;
typedef __attribute__((ext_vector_type(4))) float f32x4;

#define Bdim 2
#define Tdim 2048
#define Cdim 1024
#define Hdim 16
#define HDdim 64
#define Mdim (Bdim*Tdim)   // 4096
#define FFdim (4*Cdim)     // 4096

__device__ __forceinline__ uint16_t f2bf(float f) {
    union { float f; uint32_t u; } v; v.f = f;
    uint32_t x = v.u;
    uint32_t r = x + 0x7FFFu + ((x >> 16) & 1u);
    return (uint16_t)(r >> 16);
}
__device__ __forceinline__ float bf2f(uint16_t h) {
    union { float f; uint32_t u; } v; v.u = ((uint32_t)h) << 16; return v.f;
}

// async global->LDS, 16B per lane. dst must be wave-uniform base; HW adds lane*16.
__device__ __forceinline__ void gload_lds16(const uint16_t* g, uint16_t* l) {
    __builtin_amdgcn_global_load_lds(
        (const __attribute__((address_space(1))) void*)g,
        (__attribute__((address_space(3))) void*)l, 16, 0, 0);
}

// ---------- elementwise cast f32 -> bf16 (vectorized x4) ----------
__global__ __launch_bounds__(256) void cast4_k(const float* __restrict__ in,
                                               uint16_t* __restrict__ out) {
    int i = (blockIdx.x * 256 + threadIdx.x) * 4;
    f32x4 v = *(const f32x4*)(in + i);
    short4v o;
#pragma unroll
    for (int j = 0; j < 4; ++j) o[j] = (short)f2bf(v[j]);
    *(short4v*)(out + i) = o;
}

// ---------- tiled transpose f32(R x Cc) -> bf16(Cc x R), batched ----------
__global__ __launch_bounds__(256) void transpose_tile(const float* __restrict__ in,
                                                      uint16_t* __restrict__ out,
                                                      int R, int Cc,
                                                      size_t ibs, size_t obs) {
    __shared__ uint16_t tile[32][33];
    const float* ip = in + (size_t)blockIdx.z * ibs;
    uint16_t* op = out + (size_t)blockIdx.z * obs;
    int r0 = blockIdx.x * 32, n0 = blockIdx.y * 32;
    int tx = threadIdx.x, ty = threadIdx.y;
#pragma unroll
    for (int i = 0; i < 4; ++i) {
        int r = ty + 8 * i;
        tile[r][tx] = f2bf(ip[(size_t)(r0 + r) * Cc + n0 + tx]);
    }
    __syncthreads();
#pragma unroll
    for (int i = 0; i < 4; ++i) {
        int n = ty + 8 * i;
        op[(size_t)(n0 + n) * R + r0 + tx] = tile[tx][n];
    }
}

// ---------- per-head V transpose: qkv V slice -> vT[bh][d=64][t=T] bf16 ----------
__global__ __launch_bounds__(256) void vtrans_k(const uint16_t* __restrict__ qkv,
                                                uint16_t* __restrict__ vT) {
    __shared__ uint16_t tile[32][33];
    const int bh = blockIdx.z, b = bh >> 4, h = bh & 15;
    const uint16_t* vp = qkv + (size_t)b * Tdim * (3 * Cdim) + 2 * Cdim + h * HDdim;
    uint16_t* op = vT + (size_t)bh * HDdim * Tdim;
    const int t0 = blockIdx.x * 32, d0 = blockIdx.y * 32;
    const int tx = threadIdx.x, ty = threadIdx.y;
#pragma unroll
    for (int i = 0; i < 4; ++i) {
        int r = ty + 8 * i;
        tile[r][tx] = vp[(size_t)(t0 + r) * (3 * Cdim) + d0 + tx];
    }
    __syncthreads();
#pragma unroll
    for (int i = 0; i < 4; ++i) {
        int d = ty + 8 * i;
        op[(size_t)(d0 + d) * Tdim + t0 + tx] = tile[tx][d];
    }
}

// ---------- bf16 MFMA GEMM: C = A(MxK) * Bt(NxK)^T, fp32 accum ----------
// m97 structure: linear [128][32] LDS, global_load_lds width-16 staging, 2-barrier.
template<bool BIAS, bool RELU, bool RESID, bool OUTF>
__global__ __launch_bounds__(256) void gemm_k(const uint16_t* __restrict__ A,
                                              const uint16_t* __restrict__ Bt,
                                              int M, int N, int K,
                                              float* __restrict__ outF,
                                              uint16_t* __restrict__ outB,
                                              const float* __restrict__ bias,
                                              const float* __restrict__ resid) {
    __shared__ uint16_t As[128 * 32];
    __shared__ uint16_t Bs[128 * 32];
    const int tid = threadIdx.x;
    const int wave = tid >> 6, lane = tid & 63;
    const int lg = lane >> 4, lr = lane & 15;
    const int wm = (wave >> 1) << 6, wn = (wave & 1) << 6;
    const uint16_t* ag = A + (size_t)blockIdx.x * 128 * K + (size_t)(tid >> 2) * K + (tid & 3) * 8;
    const uint16_t* bg = Bt + (size_t)blockIdx.y * 128 * K + (size_t)(tid >> 2) * K + (tid & 3) * 8;
    const size_t rstep = (size_t)64 * K;
    uint16_t* al = As + wave * 512;
    uint16_t* bl = Bs + wave * 512;

    f32x4 acc[4][4];
#pragma unroll
    for (int i = 0; i < 4; ++i)
#pragma unroll
        for (int j = 0; j < 4; ++j) acc[i][j] = (f32x4){0.f, 0.f, 0.f, 0.f};

    for (int k0 = 0; k0 < K; k0 += 32) {
        gload_lds16(ag + k0, al);
        gload_lds16(ag + k0 + rstep, al + 2048);
        gload_lds16(bg + k0, bl);
        gload_lds16(bg + k0 + rstep, bl + 2048);
        __syncthreads();
        short8 af[4], bfr[4];
#pragma unroll
        for (int m = 0; m < 4; ++m) af[m] = *(const short8*)(As + (wm + 16 * m + lr) * 32 + 8 * lg);
#pragma unroll
        for (int n = 0; n < 4; ++n) bfr[n] = *(const short8*)(Bs + (wn + 16 * n + lr) * 32 + 8 * lg);
#pragma unroll
        for (int m = 0; m < 4; ++m)
#pragma unroll
            for (int n = 0; n < 4; ++n)
                acc[m][n] = __builtin_amdgcn_mfma_f32_16x16x32_bf16(af[m], bfr[n], acc[m][n], 0, 0, 0);
        __syncthreads();
    }
#pragma unroll
    for (int n = 0; n < 4; ++n) {
        const int col = (blockIdx.y << 7) + wn + 16 * n + lr;
        const float bv = BIAS ? bias[col] : 0.f;
#pragma unroll
        for (int m = 0; m < 4; ++m) {
#pragma unroll
            for (int r = 0; r < 4; ++r) {
                const int row = (blockIdx.x << 7) + wm + 16 * m + 4 * lg + r;
                float v = acc[m][n][r] + bv;
                if (RELU) v = fmaxf(v, 0.f);
                if (RESID) v += resid[(size_t)row * N + col];
                if (OUTF) outF[(size_t)row * N + col] = v;
                else      outB[(size_t)row * N + col] = f2bf(v);
            }
        }
    }
}

// ---------- flash attention, 4-wave blocks, LDS-staged K/V, balanced pairing ----
// Block = 256 thr = 4 waves; wave w owns 16 q-rows. Block processes supertiles
// blockIdx.x and 31-blockIdx.x (64 q-rows each) -> exactly 33 kv-chunks of 64
// for every block. K and V^T chunks staged to LDS with global_load_lds,
// double-buffered, XOR-swizzled (byte ^= (row&7)<<4) on BOTH write-source and
// read side (rule 21).
__global__ __launch_bounds__(256) void attn_k(const uint16_t* __restrict__ qkv,
                                              const uint16_t* __restrict__ vT,
                                              uint16_t* __restrict__ o) {
    __shared__ uint16_t Kb[2][64 * 64];
    __shared__ uint16_t Vb[2][64 * 64];
    const int tid = threadIdx.x;
    const int wave = tid >> 6, lane = tid & 63;
    const int lg = lane >> 4, lr = lane & 15;
    const int bh = blockIdx.y, b = bh >> 4, h = bh & 15;
    const size_t rs = 3 * Cdim;
    const uint16_t* qp = qkv + (size_t)b * Tdim * rs + (size_t)h * HDdim;
    const uint16_t* kp = qp + Cdim;
    const uint16_t* vtp = vT + (size_t)bh * HDdim * Tdim;

    // staging seg->addr: seg s covers LDS bytes 16s (linear); source element
    // group is pre-swizzled: cg_src = (s&7) ^ ((s>>3)&7), row = s>>3.
    const int s0 = tid, s1 = tid + 256;
    const int r0v = s0 >> 3, c0v = ((s0 & 7) ^ (r0v & 7)) << 3;
    const int r1v = s1 >> 3, c1v = ((s1 & 7) ^ (r1v & 7)) << 3;
    // wave-uniform LDS bases (elements): seg block [64w..64w+64) and +256
    const int db0 = wave * 512, db1 = 2048 + wave * 512;

#define STAGE(bufi, kvb)                                                        \
    do {                                                                        \
        gload_lds16(kp + (size_t)((kvb) + r0v) * rs + c0v, &Kb[bufi][db0]);     \
        gload_lds16(kp + (size_t)((kvb) + r1v) * rs + c1v, &Kb[bufi][db1]);     \
        gload_lds16(vtp + (size_t)r0v * Tdim + (kvb) + c0v, &Vb[bufi][db0]);    \
        gload_lds16(vtp + (size_t)r1v * Tdim + (kvb) + c1v, &Vb[bufi][db1]);    \
    } while (0)

    const int tiles[2] = {(int)blockIdx.x, 31 - (int)blockIdx.x};

    for (int ti = 0; ti < 2; ++ti) {
        const int tx = tiles[ti];
        const int q0 = tx << 6;            // 64 q-rows per supertile
        const int nch = tx + 1;            // kv chunks of 64
        const int qrow = q0 + 16 * wave + lr;

        // Q fragments (pre-scaled by 1/8, exact in bf16)
        short8 qf[2];
#pragma unroll
        for (int c = 0; c < 2; ++c) {
            short8 raw = *(const short8*)(qp + (size_t)qrow * rs + 32 * c + 8 * lg);
#pragma unroll
            for (int j = 0; j < 8; ++j)
                qf[c][j] = (short)f2bf(bf2f((uint16_t)raw[j]) * 0.125f);
        }

        float m_run = -__builtin_inff(), l_run = 0.f;
        f32x4 oacc[4];
#pragma unroll
        for (int t = 0; t < 4; ++t) oacc[t] = (f32x4){0.f, 0.f, 0.f, 0.f};

        STAGE(0, 0);
        __syncthreads();
        int cur = 0;
        for (int ch = 0; ch < nch; ++ch) {
            if (ch + 1 < nch) STAGE(cur ^ 1, 64 * (ch + 1));
            const int kvb = 64 * ch;
            const char* Kc = (const char*)&Kb[cur][0];
            const char* Vc = (const char*)&Vb[cur][0];
            // K fragments: row = 16u+lr (stride 128B), colgrp = lg+4c, swizzled
            short8 kf[4][2];
#pragma unroll
            for (int u = 0; u < 4; ++u)
#pragma unroll
                for (int c = 0; c < 2; ++c)
                    kf[u][c] = *(const short8*)(Kc + (16 * u + lr) * 128 +
                                                (((lg + 4 * c) ^ (lr & 7)) << 4));
            // S^T = K * Q^T : lane holds S^T[kv=16u+4lg+r][q=lr]
            f32x4 s4[4];
            __builtin_amdgcn_s_setprio(1);
#pragma unroll
            for (int u = 0; u < 4; ++u) {
                f32x4 z = (f32x4){0.f, 0.f, 0.f, 0.f};
                z = __builtin_amdgcn_mfma_f32_16x16x32_bf16(kf[u][0], qf[0], z, 0, 0, 0);
                z = __builtin_amdgcn_mfma_f32_16x16x32_bf16(kf[u][1], qf[1], z, 0, 0, 0);
                s4[u] = z;
            }
            __builtin_amdgcn_s_setprio(0);
            // online softmax (16 kv-values per lane; reduce over lg via shfl)
            float p[4][4];
            float mx = -__builtin_inff();
#pragma unroll
            for (int u = 0; u < 4; ++u)
#pragma unroll
                for (int r = 0; r < 4; ++r) {
                    int kv = kvb + 16 * u + 4 * lg + r;
                    float sv = (kv <= qrow) ? s4[u][r] : -__builtin_inff();
                    p[u][r] = sv;
                    mx = fmaxf(mx, sv);
                }
            mx = fmaxf(mx, __shfl_xor(mx, 16));
            mx = fmaxf(mx, __shfl_xor(mx, 32));
            const float m_new = fmaxf(m_run, mx);
            const float alpha = __expf(m_run - m_new);
            float ps = 0.f;
#pragma unroll
            for (int u = 0; u < 4; ++u)
#pragma unroll
                for (int r = 0; r < 4; ++r) {
                    float e = __expf(p[u][r] - m_new);
                    p[u][r] = e; ps += e;
                }
            ps += __shfl_xor(ps, 16);
            ps += __shfl_xor(ps, 32);
            l_run = l_run * alpha + ps;
            m_run = m_new;
            // P fragments, kappa'(lg,j): j<4 -> 32h+4lg+j, j>=4 -> 32h+16+4lg+j
            short8 pb[2];
#pragma unroll
            for (int hh = 0; hh < 2; ++hh)
#pragma unroll
                for (int j = 0; j < 4; ++j) {
                    pb[hh][j]     = (short)f2bf(p[2 * hh][j]);
                    pb[hh][j + 4] = (short)f2bf(p[2 * hh + 1][j]);
                }
            // O^T += V^T * P^T (V from swizzled LDS, same kappa' on kv)
            __builtin_amdgcn_s_setprio(1);
#pragma unroll
            for (int t = 0; t < 4; ++t) {
                f32x4 oa = oacc[t];
#pragma unroll
                for (int r = 0; r < 4; ++r) oa[r] *= alpha;
                const int vbase = (16 * t + lr) * 128;
                const int sw = (lr & 7) << 4;
#pragma unroll
                for (int hh = 0; hh < 2; ++hh) {
                    short4v v0 = *(const short4v*)(Vc + vbase + ((64 * hh + 8 * lg) ^ sw));
                    short4v v1 = *(const short4v*)(Vc + vbase + ((64 * hh + 32 + 8 * lg) ^ sw));
                    short8 vf = (short8){v0[0], v0[1], v0[2], v0[3], v1[0], v1[1], v1[2], v1[3]};
                    oa = __builtin_amdgcn_mfma_f32_16x16x32_bf16(vf, pb[hh], oa, 0, 0, 0);
                }
                oacc[t] = oa;
            }
            __builtin_amdgcn_s_setprio(0);
            __syncthreads();
            cur ^= 1;
        }
        // epilogue: O rows (C/D layout col=lr=q, row=4lg+r)
        const float inv = 1.f / l_run;
        uint16_t* orow = o + (size_t)(b * Tdim + qrow) * Cdim + h * HDdim;
#pragma unroll
        for (int t = 0; t < 4; ++t)
#pragma unroll
            for (int r = 0; r < 4; ++r)
                orow[16 * t + 4 * lg + r] = f2bf(oacc[t][r] * inv);
        __syncthreads();   // tile switch: buffer reuse safe
    }
#undef STAGE
}

// ---------- LayerNorm over rows of 1024, fp32 in, fp32 and/or bf16 out ----------
__global__ __launch_bounds__(256) void ln_k(const float* __restrict__ in,
                                            const float* __restrict__ g,
                                            const float* __restrict__ be,
                                            float* __restrict__ outF,
                                            uint16_t* __restrict__ outB) {
    const int row = blockIdx.x, tid = threadIdx.x;
    const float* x = in + (size_t)row * Cdim;
    f32x4 xv = *(const f32x4*)(x + tid * 4);
    float s = xv[0] + xv[1] + xv[2] + xv[3];
    float q = xv[0] * xv[0] + xv[1] * xv[1] + xv[2] * xv[2] + xv[3] * xv[3];
#pragma unroll
    for (int off = 1; off < 64; off <<= 1) { s += __shfl_xor(s, off); q += __shfl_xor(q, off); }
    __shared__ float sm[4], sq[4];
    if ((tid & 63) == 0) { sm[tid >> 6] = s; sq[tid >> 6] = q; }
    __syncthreads();
    s = sm[0] + sm[1] + sm[2] + sm[3];
    q = sq[0] + sq[1] + sq[2] + sq[3];
    const float mu = s * (1.f / 1024.f);
    const float var = q * (1.f / 1024.f) - mu * mu;
    const float rstd = rsqrtf(var + 1e-5f);
#pragma unroll
    for (int j = 0; j < 4; ++j) {
        int col = tid * 4 + j;
        float y = (xv[j] - mu) * rstd * g[col] + be[col];
        if (outF) outF[(size_t)row * Cdim + col] = y;
        if (outB) outB[(size_t)row * Cdim + col] = f2bf(y);
    }
}

// ---------- launch ----------
extern "C" void kernel_launch(void* const* d_in, const int* in_sizes, int n_in,
                              void* d_out, int out_size, void* d_ws, size_t ws_size,
                              hipStream_t stream) {
    const float* x   = (const float*)d_in[0];
    const float* Wq  = (const float*)d_in[1];
    const float* Wk  = (const float*)d_in[2];
    const float* Wv  = (const float*)d_in[3];
    const float* Wp  = (const float*)d_in[4];
    const float* bp  = (const float*)d_in[5];
    const float* W1  = (const float*)d_in[6];
    const float* b1  = (const float*)d_in[7];
    const float* W2  = (const float*)d_in[8];
    const float* b2  = (const float*)d_in[9];
    const float* g1  = (const float*)d_in[10];
    const float* be1 = (const float*)d_in[11];
    const float* g2  = (const float*)d_in[12];
    const float* be2 = (const float*)d_in[13];
    float* out = (float*)d_out;

    char* ws = (char*)d_ws;
    uint16_t* xb    = (uint16_t*)(ws + 0);          //  8 MB : x bf16
    uint16_t* wqkv  = (uint16_t*)(ws + 8388608);    //  6 MB : (3072 x 1024) packed W_qkv^T
    uint16_t* qkv   = (uint16_t*)(ws + 14680064);   // 24 MB : (4096 x 3072)
    uint16_t* obuf  = (uint16_t*)(ws + 39845888);   //  8 MB : attn out (4096 x 1024)
    uint16_t* h1    = (uint16_t*)(ws + 14680064);   // 32 MB : FFN hidden, aliases qkv+obuf (both dead)
    uint16_t* wpt   = (uint16_t*)(ws + 48234496);   //  2 MB : Wp^T
    float*    resid = (float*)   (ws + 50331648);   // 16 MB : residual (reused for both)
    uint16_t* x1b   = (uint16_t*)(ws + 67108864);   //  8 MB : ln1 out bf16
    float*    x1f   = (float*)   (ws + 75497472);   // 16 MB : ln1 out fp32 (written after attn)
    uint16_t* vT    = (uint16_t*)(ws + 75497472);   //  8 MB : V^T, aliases x1f (dead by LN1)
    uint16_t* w1t   = (uint16_t*)(ws + 92274688);   //  8 MB : W1^T
    uint16_t* w2t   = (uint16_t*)(ws + 100663296);  //  8 MB : W2^T   (total ~104 MB)

    // pack / cast
    cast4_k<<<4096, 256, 0, stream>>>(x, xb);
    transpose_tile<<<dim3(32, 2, 16), dim3(32, 8), 0, stream>>>(Wq, wqkv,           1024, 64, 65536, 65536);
    transpose_tile<<<dim3(32, 2, 16), dim3(32, 8), 0, stream>>>(Wk, wqkv + 1048576, 1024, 64, 65536, 65536);
    transpose_tile<<<dim3(32, 2, 16), dim3(32, 8), 0, stream>>>(Wv, wqkv + 2097152, 1024, 64, 65536, 65536);
    transpose_tile<<<dim3(32, 32, 1),  dim3(32, 8), 0, stream>>>(Wp, wpt, 1024, 1024, 0, 0);
    transpose_tile<<<dim3(32, 128, 1), dim3(32, 8), 0, stream>>>(W1, w1t, 1024, 4096, 0, 0);
    transpose_tile<<<dim3(128, 32, 1), dim3(32, 8), 0, stream>>>(W2, w2t, 4096, 1024, 0, 0);

    // QKV projection
    gemm_k<false, false, false, false><<<dim3(32, 24), 256, 0, stream>>>(
        xb, wqkv, Mdim, 3 * Cdim, Cdim, nullptr, qkv, nullptr, nullptr);
    // V^T pack for attention
    vtrans_k<<<dim3(64, 2, 32), dim3(32, 8), 0, stream>>>(qkv, vT);
    // attention: 16 paired supertiles x 32 bh, 256 threads
    attn_k<<<dim3(16, 32), 256, 0, stream>>>(qkv, vT, obuf);
    // output projection + bias + residual(x) -> resid (fp32)
    gemm_k<true, false, true, true><<<dim3(32, 8), 256, 0, stream>>>(
        obuf, wpt, Mdim, Cdim, Cdim, resid, nullptr, bp, x);
    // LN1 -> x1 (fp32 + bf16)
    ln_k<<<Mdim, 256, 0, stream>>>(resid, g1, be1, x1f, x1b);
    // FFN1: relu(x1 @ W1 + b1) -> h1 bf16
    gemm_k<true, true, false, false><<<dim3(32, 32), 256, 0, stream>>>(
        x1b, w1t, Mdim, FFdim, Cdim, nullptr, h1, b1, nullptr);
    // FFN2: h1 @ W2 + b2 + x1 -> resid (fp32)
    gemm_k<true, false, true, true><<<dim3(32, 8), 256, 0, stream>>>(
        h1, w2t, Mdim, Cdim, FFdim, resid, nullptr, b2, x1f);
    // LN2 -> final output fp32
    ln_k<<<Mdim, 256, 0, stream>>>(resid, g2, be2, out, nullptr);
}

// Round 4
// 315.967 us; speedup vs baseline: 1.4343x; 1.0518x over previous
//
#include <hip/hip_runtime.h>
#include <cstdint>
#include <cstddef>

// ---------- types ----------
typedef __attribute__((ext_vector_type(8))) short short8;
typedef __attribute__((ext_vector_type(4))) short short4v;
typedef __attribute__((ext_vector_type(4))) float f32x4;

#define Bdim 2
#define Tdim 2048
#define Cdim 1024
#define Hdim 16
#define HDdim 64
#define Mdim (Bdim*Tdim)   // 4096
#define FFdim (4*Cdim)     // 4096

__device__ __forceinline__ uint16_t f2bf(float f) {
    union { float f; uint32_t u; } v; v.f = f;
    uint32_t x = v.u;
    uint32_t r = x + 0x7FFFu + ((x >> 16) & 1u);
    return (uint16_t)(r >> 16);
}
__device__ __forceinline__ float bf2f(uint16_t h) {
    union { float f; uint32_t u; } v; v.u = ((uint32_t)h) << 16; return v.f;
}

// async global->LDS, 16B per lane. dst must be wave-uniform base; HW adds lane*16.
__device__ __forceinline__ void gload_lds16(const uint16_t* g, uint16_t* l) {
    __builtin_amdgcn_global_load_lds(
        (const __attribute__((address_space(1))) void*)g,
        (__attribute__((address_space(3))) void*)l, 16, 0, 0);
}

// ---------- elementwise cast f32 -> bf16 (vectorized x4) ----------
__global__ __launch_bounds__(256) void cast4_k(const float* __restrict__ in,
                                               uint16_t* __restrict__ out) {
    int i = (blockIdx.x * 256 + threadIdx.x) * 4;
    f32x4 v = *(const f32x4*)(in + i);
    short4v o;
#pragma unroll
    for (int j = 0; j < 4; ++j) o[j] = (short)f2bf(v[j]);
    *(short4v*)(out + i) = o;
}

// ---------- tiled transpose f32(R x Cc) -> bf16(Cc x R), batched ----------
__global__ __launch_bounds__(256) void transpose_tile(const float* __restrict__ in,
                                                      uint16_t* __restrict__ out,
                                                      int R, int Cc,
                                                      size_t ibs, size_t obs) {
    __shared__ uint16_t tile[32][33];
    const float* ip = in + (size_t)blockIdx.z * ibs;
    uint16_t* op = out + (size_t)blockIdx.z * obs;
    int r0 = blockIdx.x * 32, n0 = blockIdx.y * 32;
    int tx = threadIdx.x, ty = threadIdx.y;
#pragma unroll
    for (int i = 0; i < 4; ++i) {
        int r = ty + 8 * i;
        tile[r][tx] = f2bf(ip[(size_t)(r0 + r) * Cc + n0 + tx]);
    }
    __syncthreads();
#pragma unroll
    for (int i = 0; i < 4; ++i) {
        int n = ty + 8 * i;
        op[(size_t)(n0 + n) * R + r0 + tx] = tile[tx][n];
    }
}

// ---------- per-head V transpose: qkv V slice -> vT[bh][d=64][t=T] bf16 ----------
__global__ __launch_bounds__(256) void vtrans_k(const uint16_t* __restrict__ qkv,
                                                uint16_t* __restrict__ vT) {
    __shared__ uint16_t tile[32][33];
    const int bh = blockIdx.z, b = bh >> 4, h = bh & 15;
    const uint16_t* vp = qkv + (size_t)b * Tdim * (3 * Cdim) + 2 * Cdim + h * HDdim;
    uint16_t* op = vT + (size_t)bh * HDdim * Tdim;
    const int t0 = blockIdx.x * 32, d0 = blockIdx.y * 32;
    const int tx = threadIdx.x, ty = threadIdx.y;
#pragma unroll
    for (int i = 0; i < 4; ++i) {
        int r = ty + 8 * i;
        tile[r][tx] = vp[(size_t)(t0 + r) * (3 * Cdim) + d0 + tx];
    }
    __syncthreads();
#pragma unroll
    for (int i = 0; i < 4; ++i) {
        int d = ty + 8 * i;
        op[(size_t)(d0 + d) * Tdim + t0 + tx] = tile[tx][d];
    }
}

// ---------- bf16 MFMA GEMM: C = A(MxK) * Bt(NxK)^T, fp32 accum ----------
// Double-buffered 2-phase (T3 minimum): STAGE(t+1) issued BEFORE compute(t),
// single barrier per K-step (compiler emits vmcnt(0)+lgkmcnt(0) at barrier).
template<bool BIAS, bool RELU, bool RESID, bool OUTF>
__global__ __launch_bounds__(256) void gemm_k(const uint16_t* __restrict__ A,
                                              const uint16_t* __restrict__ Bt,
                                              int M, int N, int K,
                                              float* __restrict__ outF,
                                              uint16_t* __restrict__ outB,
                                              const float* __restrict__ bias,
                                              const float* __restrict__ resid) {
    __shared__ uint16_t As[2][128 * 32];
    __shared__ uint16_t Bs[2][128 * 32];
    const int tid = threadIdx.x;
    const int wave = tid >> 6, lane = tid & 63;
    const int lg = lane >> 4, lr = lane & 15;
    const int wm = (wave >> 1) << 6, wn = (wave & 1) << 6;
    const uint16_t* ag = A + (size_t)blockIdx.x * 128 * K + (size_t)(tid >> 2) * K + (tid & 3) * 8;
    const uint16_t* bg = Bt + (size_t)blockIdx.y * 128 * K + (size_t)(tid >> 2) * K + (tid & 3) * 8;
    const size_t rstep = (size_t)64 * K;
    const int db0 = wave * 512, db1 = 2048 + wave * 512;   // wave-uniform LDS offsets

    f32x4 acc[4][4];
#pragma unroll
    for (int i = 0; i < 4; ++i)
#pragma unroll
        for (int j = 0; j < 4; ++j) acc[i][j] = (f32x4){0.f, 0.f, 0.f, 0.f};

#define GSTAGE(bi, kk)                                     \
    do {                                                   \
        gload_lds16(ag + (kk), &As[bi][db0]);              \
        gload_lds16(ag + (kk) + rstep, &As[bi][db1]);      \
        gload_lds16(bg + (kk), &Bs[bi][db0]);              \
        gload_lds16(bg + (kk) + rstep, &Bs[bi][db1]);      \
    } while (0)

    GSTAGE(0, 0);
    __syncthreads();                 // vmcnt(0): buffer 0 ready
    int cur = 0;
    for (int k0 = 0; k0 < K; k0 += 32) {
        if (k0 + 32 < K) GSTAGE(cur ^ 1, k0 + 32);   // prefetch next tile first
        short8 af[4], bfr[4];
#pragma unroll
        for (int m = 0; m < 4; ++m) af[m] = *(const short8*)(&As[cur][0] + (wm + 16 * m + lr) * 32 + 8 * lg);
#pragma unroll
        for (int n = 0; n < 4; ++n) bfr[n] = *(const short8*)(&Bs[cur][0] + (wn + 16 * n + lr) * 32 + 8 * lg);
#pragma unroll
        for (int m = 0; m < 4; ++m)
#pragma unroll
            for (int n = 0; n < 4; ++n)
                acc[m][n] = __builtin_amdgcn_mfma_f32_16x16x32_bf16(af[m], bfr[n], acc[m][n], 0, 0, 0);
        __syncthreads();             // drains prefetch (vmcnt 0) + lgkm; 1 barrier/step
        cur ^= 1;
    }
#undef GSTAGE
#pragma unroll
    for (int n = 0; n < 4; ++n) {
        const int col = (blockIdx.y << 7) + wn + 16 * n + lr;
        const float bv = BIAS ? bias[col] : 0.f;
#pragma unroll
        for (int m = 0; m < 4; ++m) {
#pragma unroll
            for (int r = 0; r < 4; ++r) {
                const int row = (blockIdx.x << 7) + wm + 16 * m + 4 * lg + r;
                float v = acc[m][n][r] + bv;
                if (RELU) v = fmaxf(v, 0.f);
                if (RESID) v += resid[(size_t)row * N + col];
                if (OUTF) outF[(size_t)row * N + col] = v;
                else      outB[(size_t)row * N + col] = f2bf(v);
            }
        }
    }
}

// ---------- flash attention, 4-wave blocks, LDS-staged K/V, balanced pairing ----
__global__ __launch_bounds__(256) void attn_k(const uint16_t* __restrict__ qkv,
                                              const uint16_t* __restrict__ vT,
                                              uint16_t* __restrict__ o) {
    __shared__ uint16_t Kb[2][64 * 64];
    __shared__ uint16_t Vb[2][64 * 64];
    const int tid = threadIdx.x;
    const int wave = tid >> 6, lane = tid & 63;
    const int lg = lane >> 4, lr = lane & 15;
    const int bh = blockIdx.y, b = bh >> 4, h = bh & 15;
    const size_t rs = 3 * Cdim;
    const uint16_t* qp = qkv + (size_t)b * Tdim * rs + (size_t)h * HDdim;
    const uint16_t* kp = qp + Cdim;
    const uint16_t* vtp = vT + (size_t)bh * HDdim * Tdim;

    const int s0 = tid, s1 = tid + 256;
    const int r0v = s0 >> 3, c0v = ((s0 & 7) ^ (r0v & 7)) << 3;
    const int r1v = s1 >> 3, c1v = ((s1 & 7) ^ (r1v & 7)) << 3;
    const int db0 = wave * 512, db1 = 2048 + wave * 512;

#define STAGE(bufi, kvb)                                                        \
    do {                                                                        \
        gload_lds16(kp + (size_t)((kvb) + r0v) * rs + c0v, &Kb[bufi][db0]);     \
        gload_lds16(kp + (size_t)((kvb) + r1v) * rs + c1v, &Kb[bufi][db1]);     \
        gload_lds16(vtp + (size_t)r0v * Tdim + (kvb) + c0v, &Vb[bufi][db0]);    \
        gload_lds16(vtp + (size_t)r1v * Tdim + (kvb) + c1v, &Vb[bufi][db1]);    \
    } while (0)

    const int tiles[2] = {(int)blockIdx.x, 31 - (int)blockIdx.x};

    for (int ti = 0; ti < 2; ++ti) {
        const int tx = tiles[ti];
        const int q0 = tx << 6;
        const int nch = tx + 1;
        const int qrow = q0 + 16 * wave + lr;

        short8 qf[2];
#pragma unroll
        for (int c = 0; c < 2; ++c) {
            short8 raw = *(const short8*)(qp + (size_t)qrow * rs + 32 * c + 8 * lg);
#pragma unroll
            for (int j = 0; j < 8; ++j)
                qf[c][j] = (short)f2bf(bf2f((uint16_t)raw[j]) * 0.125f);
        }

        float m_run = -__builtin_inff(), l_run = 0.f;
        f32x4 oacc[4];
#pragma unroll
        for (int t = 0; t < 4; ++t) oacc[t] = (f32x4){0.f, 0.f, 0.f, 0.f};

        STAGE(0, 0);
        __syncthreads();
        int cur = 0;
        for (int ch = 0; ch < nch; ++ch) {
            if (ch + 1 < nch) STAGE(cur ^ 1, 64 * (ch + 1));
            const int kvb = 64 * ch;
            const char* Kc = (const char*)&Kb[cur][0];
            const char* Vc = (const char*)&Vb[cur][0];
            short8 kf[4][2];
#pragma unroll
            for (int u = 0; u < 4; ++u)
#pragma unroll
                for (int c = 0; c < 2; ++c)
                    kf[u][c] = *(const short8*)(Kc + (16 * u + lr) * 128 +
                                                (((lg + 4 * c) ^ (lr & 7)) << 4));
            f32x4 s4[4];
            __builtin_amdgcn_s_setprio(1);
#pragma unroll
            for (int u = 0; u < 4; ++u) {
                f32x4 z = (f32x4){0.f, 0.f, 0.f, 0.f};
                z = __builtin_amdgcn_mfma_f32_16x16x32_bf16(kf[u][0], qf[0], z, 0, 0, 0);
                z = __builtin_amdgcn_mfma_f32_16x16x32_bf16(kf[u][1], qf[1], z, 0, 0, 0);
                s4[u] = z;
            }
            __builtin_amdgcn_s_setprio(0);
            float p[4][4];
            float mx = -__builtin_inff();
#pragma unroll
            for (int u = 0; u < 4; ++u)
#pragma unroll
                for (int r = 0; r < 4; ++r) {
                    int kv = kvb + 16 * u + 4 * lg + r;
                    float sv = (kv <= qrow) ? s4[u][r] : -__builtin_inff();
                    p[u][r] = sv;
                    mx = fmaxf(mx, sv);
                }
            mx = fmaxf(mx, __shfl_xor(mx, 16));
            mx = fmaxf(mx, __shfl_xor(mx, 32));
            const float m_new = fmaxf(m_run, mx);
            const float alpha = __expf(m_run - m_new);
            float ps = 0.f;
#pragma unroll
            for (int u = 0; u < 4; ++u)
#pragma unroll
                for (int r = 0; r < 4; ++r) {
                    float e = __expf(p[u][r] - m_new);
                    p[u][r] = e; ps += e;
                }
            ps += __shfl_xor(ps, 16);
            ps += __shfl_xor(ps, 32);
            l_run = l_run * alpha + ps;
            m_run = m_new;
            short8 pb[2];
#pragma unroll
            for (int hh = 0; hh < 2; ++hh)
#pragma unroll
                for (int j = 0; j < 4; ++j) {
                    pb[hh][j]     = (short)f2bf(p[2 * hh][j]);
                    pb[hh][j + 4] = (short)f2bf(p[2 * hh + 1][j]);
                }
            __builtin_amdgcn_s_setprio(1);
#pragma unroll
            for (int t = 0; t < 4; ++t) {
                f32x4 oa = oacc[t];
#pragma unroll
                for (int r = 0; r < 4; ++r) oa[r] *= alpha;
                const int vbase = (16 * t + lr) * 128;
                const int sw = (lr & 7) << 4;
#pragma unroll
                for (int hh = 0; hh < 2; ++hh) {
                    short4v v0 = *(const short4v*)(Vc + vbase + ((64 * hh + 8 * lg) ^ sw));
                    short4v v1 = *(const short4v*)(Vc + vbase + ((64 * hh + 32 + 8 * lg) ^ sw));
                    short8 vf = (short8){v0[0], v0[1], v0[2], v0[3], v1[0], v1[1], v1[2], v1[3]};
                    oa = __builtin_amdgcn_mfma_f32_16x16x32_bf16(vf, pb[hh], oa, 0, 0, 0);
                }
                oacc[t] = oa;
            }
            __builtin_amdgcn_s_setprio(0);
            __syncthreads();
            cur ^= 1;
        }
        const float inv = 1.f / l_run;
        uint16_t* orow = o + (size_t)(b * Tdim + qrow) * Cdim + h * HDdim;
#pragma unroll
        for (int t = 0; t < 4; ++t)
#pragma unroll
            for (int r = 0; r < 4; ++r)
                orow[16 * t + 4 * lg + r] = f2bf(oacc[t][r] * inv);
        __syncthreads();
    }
#undef STAGE
}

// ---------- LayerNorm over rows of 1024, fp32 in, fp32 and/or bf16 out ----------
__global__ __launch_bounds__(256) void ln_k(const float* __restrict__ in,
                                            const float* __restrict__ g,
                                            const float* __restrict__ be,
                                            float* __restrict__ outF,
                                            uint16_t* __restrict__ outB) {
    const int row = blockIdx.x, tid = threadIdx.x;
    const float* x = in + (size_t)row * Cdim;
    f32x4 xv = *(const f32x4*)(x + tid * 4);
    float s = xv[0] + xv[1] + xv[2] + xv[3];
    float q = xv[0] * xv[0] + xv[1] * xv[1] + xv[2] * xv[2] + xv[3] * xv[3];
#pragma unroll
    for (int off = 1; off < 64; off <<= 1) { s += __shfl_xor(s, off); q += __shfl_xor(q, off); }
    __shared__ float sm[4], sq[4];
    if ((tid & 63) == 0) { sm[tid >> 6] = s; sq[tid >> 6] = q; }
    __syncthreads();
    s = sm[0] + sm[1] + sm[2] + sm[3];
    q = sq[0] + sq[1] + sq[2] + sq[3];
    const float mu = s * (1.f / 1024.f);
    const float var = q * (1.f / 1024.f) - mu * mu;
    const float rstd = rsqrtf(var + 1e-5f);
#pragma unroll
    for (int j = 0; j < 4; ++j) {
        int col = tid * 4 + j;
        float y = (xv[j] - mu) * rstd * g[col] + be[col];
        if (outF) outF[(size_t)row * Cdim + col] = y;
        if (outB) outB[(size_t)row * Cdim + col] = f2bf(y);
    }
}

// ---------- launch ----------
extern "C" void kernel_launch(void* const* d_in, const int* in_sizes, int n_in,
                              void* d_out, int out_size, void* d_ws, size_t ws_size,
                              hipStream_t stream) {
    const float* x   = (const float*)d_in[0];
    const float* Wq  = (const float*)d_in[1];
    const float* Wk  = (const float*)d_in[2];
    const float* Wv  = (const float*)d_in[3];
    const float* Wp  = (const float*)d_in[4];
    const float* bp  = (const float*)d_in[5];
    const float* W1  = (const float*)d_in[6];
    const float* b1  = (const float*)d_in[7];
    const float* W2  = (const float*)d_in[8];
    const float* b2  = (const float*)d_in[9];
    const float* g1  = (const float*)d_in[10];
    const float* be1 = (const float*)d_in[11];
    const float* g2  = (const float*)d_in[12];
    const float* be2 = (const float*)d_in[13];
    float* out = (float*)d_out;

    char* ws = (char*)d_ws;
    uint16_t* xb    = (uint16_t*)(ws + 0);          //  8 MB : x bf16
    uint16_t* wqkv  = (uint16_t*)(ws + 8388608);    //  6 MB : (3072 x 1024) packed W_qkv^T
    uint16_t* qkv   = (uint16_t*)(ws + 14680064);   // 24 MB : (4096 x 3072)
    uint16_t* obuf  = (uint16_t*)(ws + 39845888);   //  8 MB : attn out (4096 x 1024)
    uint16_t* h1    = (uint16_t*)(ws + 14680064);   // 32 MB : FFN hidden, aliases qkv+obuf (both dead)
    uint16_t* wpt   = (uint16_t*)(ws + 48234496);   //  2 MB : Wp^T
    float*    resid = (float*)   (ws + 50331648);   // 16 MB : residual (reused for both)
    uint16_t* x1b   = (uint16_t*)(ws + 67108864);   //  8 MB : ln1 out bf16
    float*    x1f   = (float*)   (ws + 75497472);   // 16 MB : ln1 out fp32 (written after attn)
    uint16_t* vT    = (uint16_t*)(ws + 75497472);   //  8 MB : V^T, aliases x1f (dead by LN1)
    uint16_t* w1t   = (uint16_t*)(ws + 92274688);   //  8 MB : W1^T
    uint16_t* w2t   = (uint16_t*)(ws + 100663296);  //  8 MB : W2^T   (total ~104 MB)

    // pack / cast
    cast4_k<<<4096, 256, 0, stream>>>(x, xb);
    transpose_tile<<<dim3(32, 2, 16), dim3(32, 8), 0, stream>>>(Wq, wqkv,           1024, 64, 65536, 65536);
    transpose_tile<<<dim3(32, 2, 16), dim3(32, 8), 0, stream>>>(Wk, wqkv + 1048576, 1024, 64, 65536, 65536);
    transpose_tile<<<dim3(32, 2, 16), dim3(32, 8), 0, stream>>>(Wv, wqkv + 2097152, 1024, 64, 65536, 65536);
    transpose_tile<<<dim3(32, 32, 1),  dim3(32, 8), 0, stream>>>(Wp, wpt, 1024, 1024, 0, 0);
    transpose_tile<<<dim3(32, 128, 1), dim3(32, 8), 0, stream>>>(W1, w1t, 1024, 4096, 0, 0);
    transpose_tile<<<dim3(128, 32, 1), dim3(32, 8), 0, stream>>>(W2, w2t, 4096, 1024, 0, 0);

    // QKV projection
    gemm_k<false, false, false, false><<<dim3(32, 24), 256, 0, stream>>>(
        xb, wqkv, Mdim, 3 * Cdim, Cdim, nullptr, qkv, nullptr, nullptr);
    // V^T pack for attention
    vtrans_k<<<dim3(64, 2, 32), dim3(32, 8), 0, stream>>>(qkv, vT);
    // attention: 16 paired supertiles x 32 bh, 256 threads
    attn_k<<<dim3(16, 32), 256, 0, stream>>>(qkv, vT, obuf);
    // output projection + bias + residual(x) -> resid (fp32)
    gemm_k<true, false, true, true><<<dim3(32, 8), 256, 0, stream>>>(
        obuf, wpt, Mdim, Cdim, Cdim, resid, nullptr, bp, x);
    // LN1 -> x1 (fp32 + bf16)
    ln_k<<<Mdim, 256, 0, stream>>>(resid, g1, be1, x1f, x1b);
    // FFN1: relu(x1 @ W1 + b1) -> h1 bf16
    gemm_k<true, true, false, false><<<dim3(32, 32), 256, 0, stream>>>(
        x1b, w1t, Mdim, FFdim, Cdim, nullptr, h1, b1, nullptr);
    // FFN2: h1 @ W2 + b2 + x1 -> resid (fp32)
    gemm_k<true, false, true, true><<<dim3(32, 8), 256, 0, stream>>>(
        h1, w2t, Mdim, Cdim, FFdim, resid, nullptr, b2, x1f);
    // LN2 -> final output fp32
    ln_k<<<Mdim, 256, 0, stream>>>(resid, g2, be2, out, nullptr);
}